// Round 6
// baseline (746.107 us; speedup 1.0000x reference)
//
#include <hip/hip_runtime.h>
#include <stdint.h>

#define HEADS 16
#define BSZ 512
#define NTOK 65
#define MTOK (BSZ * NTOK)   // 33280 = 260*128 = 130*256
#define NX  34078720UL      // x elems
#define NQW 3145728UL       // w_qkv elems
#define NPW 1048576UL       // w_proj elems

typedef __attribute__((ext_vector_type(8))) short bf16x8;
typedef __attribute__((ext_vector_type(4))) float f32x4;

__device__ __forceinline__ unsigned short f2bf(float f) {
  unsigned u = __float_as_uint(f);
  u += 0x7FFFu + ((u >> 16) & 1u);          // RNE
  return (unsigned short)(u >> 16);
}

// ---------------- fp32 -> bf16 cast of x, w_qkv, w_proj ----------------
__global__ __launch_bounds__(256) void cast3_kernel(
    const float* __restrict__ x, const float* __restrict__ wq, const float* __restrict__ wp,
    unsigned short* __restrict__ xb, unsigned short* __restrict__ wqb, unsigned short* __restrict__ wpb) {
  size_t u = ((size_t)blockIdx.x * 256 + threadIdx.x) * 4;
  const float* src; unsigned short* dst; size_t off;
  if (u < NX)            { src = x;  dst = xb;  off = u; }
  else if (u < NX + NQW) { src = wq; dst = wqb; off = u - NX; }
  else                   { src = wp; dst = wpb; off = u - NX - NQW; }
  float4 v = *(const float4*)(src + off);
  ushort4 o;
  o.x = f2bf(v.x); o.y = f2bf(v.y); o.z = f2bf(v.z); o.w = f2bf(v.w);
  *(ushort4*)(dst + off) = o;
}

// ========= 256x256-tile bf16 GEMM (C = A[M,1024] @ B[N,1024]^T), 8 waves =========
// R1/R4-verified structure (335 us on gemm0): BK=64, double-buffered 128 KB LDS,
// stage tile t+1 into the DEAD buffer at the top of tile t's compute, 4 phases of
// {ds_read subtile; s_barrier; setprio(1); 16 MFMA; setprio(0)}, boundary
// __syncthreads() drain. Chunk-XOR swizzle (0 bank conflicts measured).
// Race-free: writes only buf^1, reads only buf, one fence per K-tile.
// NOTE: counted-vmcnt variants tried twice (R2, R4) — one regressed (broke load
// coalescing at BK=32), one corrupted (4-phase ledger unverifiable) — keep this.
// MODE 0: fused LayerNorm epilogue + q/k/v scatter (NBN=12). MODE 1: fp32 out (NBN=4).
template <int MODE, int NBN>
__global__ __launch_bounds__(512, 2) void gemm256_kernel(
    const unsigned short* __restrict__ A, const unsigned short* __restrict__ Bm,
    unsigned short* __restrict__ qws, unsigned short* __restrict__ kws,
    unsigned short* __restrict__ vws, float* __restrict__ outp,
    const float* __restrict__ qn_w, const float* __restrict__ qn_b,
    const float* __restrict__ kn_w, const float* __restrict__ kn_b) {
  __shared__ unsigned short As0[256 * 64];
  __shared__ unsigned short Bs0[256 * 64];
  __shared__ unsigned short As1[256 * 64];
  __shared__ unsigned short Bs1[256 * 64];
  const int tid = threadIdx.x;
  const int wid = tid >> 6, lane = tid & 63;
  const int lrow = lane & 15, lk = lane >> 4;
  const int wm = wid >> 2, wn = wid & 3;

  // XCD-aware bijective swizzle (gridDim.x % 8 == 0 for both launches)
  const int chunk = (int)gridDim.x >> 3;
  const int orig = blockIdx.x;
  const int wg = (orig & 7) * chunk + (orig >> 3);
  const int bm = wg / NBN, bn = wg - bm * NBN;

  const size_t arow0 = (size_t)bm * 256, brow0 = (size_t)bn * 256;

  // per-thread staging sources: 4 chunks of A + 4 of B per K-tile
  const unsigned short* pA[4];
  const unsigned short* pB[4];
  int dstc[4];
#pragma unroll
  for (int j = 0; j < 4; ++j) {
    int ci = j * 512 + tid;
    int row = ci >> 3;
    int k8 = (ci & 7) ^ (row & 7);           // logical k-chunk stored at slot ci&7
    pA[j] = A + (arow0 + row) * 1024 + k8 * 8;
    pB[j] = Bm + (brow0 + row) * 1024 + k8 * 8;
    dstc[j] = (j * 512 + wid * 64) * 4;      // uint units (wave-uniform base)
  }

  f32x4 acc[2][4][4] = {};

  auto stage = [&](unsigned short* __restrict__ dA, unsigned short* __restrict__ dB, int ktn) {
    const int koff = ktn * 64;
#pragma unroll
    for (int j = 0; j < 4; ++j) {
      __builtin_amdgcn_global_load_lds(
          (const __attribute__((address_space(1))) unsigned int*)(pA[j] + koff),
          (__attribute__((address_space(3))) unsigned int*)dA + dstc[j], 16, 0, 0);
      __builtin_amdgcn_global_load_lds(
          (const __attribute__((address_space(1))) unsigned int*)(pB[j] + koff),
          (__attribute__((address_space(3))) unsigned int*)dB + dstc[j], 16, 0, 0);
    }
  };

  auto ktile = [&](const unsigned short* __restrict__ RA, const unsigned short* __restrict__ RB,
                   unsigned short* __restrict__ WA, unsigned short* __restrict__ WB, int ktn) {
    if (ktn < 16) stage(WA, WB, ktn);        // prefetch next K-tile into dead buffer
#pragma unroll
    for (int kk = 0; kk < 2; ++kk) {
      const int cpos8 = ((kk * 4 + lk) ^ (lrow & 7)) * 8;
      bf16x8 bv[4];
#pragma unroll
      for (int nt = 0; nt < 4; ++nt)
        bv[nt] = *(const bf16x8*)&RB[(wn * 64 + nt * 16 + lrow) * 64 + cpos8];
#pragma unroll
      for (int mh = 0; mh < 2; ++mh) {       // phase: 4 ds_read A + 16 MFMA
        bf16x8 av[4];
#pragma unroll
        for (int mt = 0; mt < 4; ++mt)
          av[mt] = *(const bf16x8*)&RA[(wm * 128 + mh * 64 + mt * 16 + lrow) * 64 + cpos8];
        __builtin_amdgcn_s_barrier();
        __builtin_amdgcn_s_setprio(1);
#pragma unroll
        for (int mt = 0; mt < 4; ++mt)
#pragma unroll
          for (int nt = 0; nt < 4; ++nt)
            acc[mh][mt][nt] =
                __builtin_amdgcn_mfma_f32_16x16x32_bf16(av[mt], bv[nt], acc[mh][mt][nt], 0, 0, 0);
        __builtin_amdgcn_s_setprio(0);
      }
    }
    __syncthreads();                          // vmcnt(0)+lgkmcnt(0)+barrier: kt+1 ready
  };

  stage(As0, Bs0, 0);                         // prologue
  __syncthreads();

#pragma unroll 1
  for (int kt2 = 0; kt2 < 8; ++kt2) {
    ktile(As0, Bs0, As1, Bs1, 2 * kt2 + 1);
    ktile(As1, Bs1, As0, Bs0, 2 * kt2 + 2);
  }

  if (MODE == 0) {
    // ---- fused LN epilogue + q/k/v scatter (256-wide tile indexing) ----
    const int sec = bn >> 2;                  // 0:q 1:k 2:v (block-uniform; 4 tiles/sec)
    const int h0 = ((bn & 3) << 2) + wn;      // head (wave-uniform; wave = one head)
    const float qsc = (sec == 0) ? 0.125f : 1.0f;
    float wv[4], bvv[4];
    if (sec < 2) {
      const float* wp_ = sec ? kn_w : qn_w;
      const float* bp_ = sec ? kn_b : qn_b;
#pragma unroll
      for (int nt = 0; nt < 4; ++nt) {
        wv[nt] = wp_[nt * 16 + lrow];
        bvv[nt] = bp_[nt * 16 + lrow];
      }
    }
    unsigned short* qk_dst = sec ? kws : qws;
#pragma unroll
    for (int mh = 0; mh < 2; ++mh)
#pragma unroll
      for (int mt = 0; mt < 4; ++mt)
#pragma unroll
        for (int r = 0; r < 4; ++r) {
          int grow = bm * 256 + wm * 128 + mh * 64 + mt * 16 + lk * 4 + r;
          int b = grow / 65, nn = grow - b * 65;   // const div -> magic mul
          int bh = b * HEADS + h0;
          if (sec < 2) {
            float s = 0.f, s2 = 0.f;
#pragma unroll
            for (int nt = 0; nt < 4; ++nt) {
              float f = acc[mh][mt][nt][r];
              s += f; s2 += f * f;
            }
            s += __shfl_xor(s, 1); s2 += __shfl_xor(s2, 1);
            s += __shfl_xor(s, 2); s2 += __shfl_xor(s2, 2);
            s += __shfl_xor(s, 4); s2 += __shfl_xor(s2, 4);
            s += __shfl_xor(s, 8); s2 += __shfl_xor(s2, 8);
            float mu = s * 0.015625f;
            float rstd = rsqrtf(s2 * 0.015625f - mu * mu + 1e-5f);
            size_t base = ((size_t)bh * 65 + nn) * 64;
#pragma unroll
            for (int nt = 0; nt < 4; ++nt)
              qk_dst[base + nt * 16 + lrow] =
                  f2bf(((acc[mh][mt][nt][r] - mu) * rstd * wv[nt] + bvv[nt]) * qsc);
          } else {
#pragma unroll
            for (int nt = 0; nt < 4; ++nt)
              vws[((size_t)bh * 64 + nt * 16 + lrow) * 80 + nn] = f2bf(acc[mh][mt][nt][r]);
          }
        }
  } else {
    // ---- fp32 store epilogue ----
    const size_t cb = (size_t)bn * 256 + wn * 64 + lrow;
#pragma unroll
    for (int mh = 0; mh < 2; ++mh)
#pragma unroll
      for (int mt = 0; mt < 4; ++mt)
#pragma unroll
        for (int r = 0; r < 4; ++r) {
          float* rp = outp +
              (size_t)(bm * 256 + wm * 128 + mh * 64 + mt * 16 + lk * 4 + r) * 1024 + cb;
#pragma unroll
          for (int nt = 0; nt < 4; ++nt) rp[nt * 16] = acc[mh][mt][nt][r];
        }
  }
}

// ---------------- attention per (b,h): S=qk^T, softmax, O=PV ----------------
// q,k already LayerNormed (+q scale) by gemm0. q/k staged via global_load_lds.
// V is NOT LDS-staged (m169: staging L2-resident data is pure overhead) — PV
// reads V-fragments directly from global vws (each block touches its own
// ~10 KB slice <=5x; L2/L3-hot). LDS = 20 KB (qk region, reused for P after
// QK^T) -> occupancy now VGPR-capped: launch_bounds(256,5) -> 5 blocks/CU.
__global__ __launch_bounds__(256, 5) void attn_kernel(
    const unsigned short* __restrict__ qws, const unsigned short* __restrict__ kws,
    const unsigned short* __restrict__ vws,
    const float* __restrict__ bias, const float* __restrict__ bias_scale,
    unsigned short* __restrict__ aws) {
  __shared__ unsigned short qk_s[2 * 80 * 64];  // phase A: q rows 0..79 | k rows 0..79
                                                // phase B: P (80 x 128, swizzled chunks)
  const int tid = threadIdx.x;
  const int wid = tid >> 6;
  const int bh = blockIdx.x;
  const int b = bh >> 4, h = bh & 15;
  const size_t qbase = (size_t)bh * 65 * 64;
  const size_t vbase = (size_t)bh * 64 * 80;

  // async stage q,k rows 0..63 (512 chunks each, 2 rounds of 256)
#pragma unroll
  for (int it = 0; it < 2; ++it) {
    int ci = it * 256 + tid;
    int row = ci >> 3, k8s = ci & 7;
    int k8 = k8s ^ (row & 7);
    __builtin_amdgcn_global_load_lds(
        (const __attribute__((address_space(1))) unsigned int*)(qws + qbase + row * 64 + k8 * 8),
        (__attribute__((address_space(3))) unsigned int*)qk_s + (size_t)(it * 256 + wid * 64) * 4,
        16, 0, 0);
    __builtin_amdgcn_global_load_lds(
        (const __attribute__((address_space(1))) unsigned int*)(kws + qbase + row * 64 + k8 * 8),
        (__attribute__((address_space(3))) unsigned int*)qk_s + (size_t)(640 + it * 256 + wid * 64) * 4,
        16, 0, 0);
  }
  // row 64 (8 chunks each) via plain copy; row&7==0 so no swizzle change.
  // q/k rows 65..79 stay uninitialized: S cols>=65 are masked to -1e30 before use,
  // and S rows>=65 only ever feed O rows>=65 which are never stored.
  if (tid < 8) {
    bf16x8 tq = *(const bf16x8*)&qws[qbase + 64 * 64 + tid * 8];
    *(bf16x8*)&qk_s[64 * 64 + tid * 8] = tq;
  } else if (tid < 16) {
    int t = tid - 8;
    bf16x8 tk = *(const bf16x8*)&kws[qbase + 64 * 64 + t * 8];
    *(bf16x8*)&qk_s[5120 + 64 * 64 + t * 8] = tk;
  }
  __syncthreads();

  const int lane = tid & 63;
  const int lrow = lane & 15, lk = lane >> 4;
  const float bsc = *bias_scale;
  const unsigned short* q_s = qk_s;
  const unsigned short* k_s = qk_s + 5120;
  unsigned short* p_s = qk_s;                     // P overlays q|k after the barrier

  // S = q@k^T (+bias, mask) then softmax, packed bf16 held in registers.
  auto qkt_softmax = [&](int s, unsigned int (&pk)[5][2]) {
    f32x4 accs[5] = {};
#pragma unroll
    for (int kk = 0; kk < 2; ++kk) {
      const int cpos = (kk * 4 + lk) ^ (lrow & 7);
      bf16x8 af = *(const bf16x8*)&q_s[(s * 16 + lrow) * 64 + cpos * 8];
#pragma unroll
      for (int nt = 0; nt < 5; ++nt) {
        bf16x8 bv = *(const bf16x8*)&k_s[(nt * 16 + lrow) * 64 + cpos * 8];
        accs[nt] = __builtin_amdgcn_mfma_f32_16x16x32_bf16(af, bv, accs[nt], 0, 0, 0);
      }
    }
#pragma unroll
    for (int r = 0; r < 4; ++r) {
      int row = s * 16 + lk * 4 + r;
      int brow = row > 64 ? 64 : row;
      float vals[5];
#pragma unroll
      for (int nt = 0; nt < 5; ++nt) {
        int col = nt * 16 + lrow;
        float v = accs[nt][r];
        if (col < 65) v += bias[((size_t)h * 65 + brow) * 65 + col] * bsc;
        else v = -1e30f;
        vals[nt] = v;
      }
      float m = vals[0];
#pragma unroll
      for (int nt = 1; nt < 5; ++nt) m = fmaxf(m, vals[nt]);
      m = fmaxf(m, __shfl_xor(m, 1)); m = fmaxf(m, __shfl_xor(m, 2));
      m = fmaxf(m, __shfl_xor(m, 4)); m = fmaxf(m, __shfl_xor(m, 8));
      float ssum = 0.f;
#pragma unroll
      for (int nt = 0; nt < 5; ++nt) { vals[nt] = __expf(vals[nt] - m); ssum += vals[nt]; }
      ssum += __shfl_xor(ssum, 1); ssum += __shfl_xor(ssum, 2);
      ssum += __shfl_xor(ssum, 4); ssum += __shfl_xor(ssum, 8);
      float inv = 1.0f / ssum;
#pragma unroll
      for (int nt = 0; nt < 5; ++nt) {
        unsigned int u = (unsigned int)f2bf(vals[nt] * inv);
        if ((r & 1) == 0) pk[nt][r >> 1] = u;
        else pk[nt][r >> 1] |= u << 16;
      }
    }
  };

  auto pwrite = [&](int s, const unsigned int (&pk)[5][2]) {
#pragma unroll
    for (int r = 0; r < 4; ++r) {
      int row = s * 16 + lk * 4 + r;
#pragma unroll
      for (int nt = 0; nt < 5; ++nt) {
        int col = nt * 16 + lrow;
        p_s[row * 128 + ((col >> 3) ^ (row & 7)) * 8 + (col & 7)] =
            (unsigned short)(pk[nt][r >> 1] >> ((r & 1) * 16));
      }
      // cols 80..95 must be exact zero (PV k-step 2 covers cols 64..95);
      // chunks 12..15 (cols 96..127) are never read by PV -> not written.
#pragma unroll
      for (int nt = 5; nt < 6; ++nt) {
        int col = nt * 16 + lrow;
        p_s[row * 128 + ((col >> 3) ^ (row & 7)) * 8 + (col & 7)] = 0;
      }
    }
  };

  unsigned int pk0[5][2], pk1[5][2];
  qkt_softmax(wid, pk0);
  if (wid == 0) qkt_softmax(4, pk1);
  __syncthreads();                 // all q/k reads complete before P overlays them
  pwrite(wid, pk0);
  if (wid == 0) pwrite(4, pk1);
  __syncthreads();

  // O = P @ V, k-dim 96 (P cols 65..95 exact zero). V^T fragments read directly
  // from global vws [bh][d=64][n=80]: row = d (nt*16+lrow), chunk = kk*4+lk
  // (no swizzle; 16B aligned: row*160B + chunk*16B). Reads n up to 95 spill into
  // the next d-row's elems — finite bf16, multiplied by exact-zero P cols.
  const unsigned short* vp = vws + vbase;
  const size_t obase = (size_t)b * 65 * 1024 + h * 64;
  for (int s = wid; s < 5; s += 4) {
    f32x4 acco[4] = {};
#pragma unroll
    for (int kk = 0; kk < 3; ++kk) {
      const int lc = kk * 4 + lk;                    // logical n-chunk 0..11
      const int cpos = lc ^ (lrow & 7);
      bf16x8 af = *(const bf16x8*)&p_s[(s * 16 + lrow) * 128 + cpos * 8];
#pragma unroll
      for (int nt = 0; nt < 4; ++nt) {
        bf16x8 bv = *(const bf16x8*)&vp[(nt * 16 + lrow) * 80 + lc * 8];
        acco[nt] = __builtin_amdgcn_mfma_f32_16x16x32_bf16(af, bv, acco[nt], 0, 0, 0);
      }
    }
#pragma unroll
    for (int r = 0; r < 4; ++r) {
      int row = s * 16 + lk * 4 + r;
      if (row < 65) {
#pragma unroll
        for (int nt = 0; nt < 4; ++nt)
          aws[obase + (size_t)row * 1024 + nt * 16 + lrow] = f2bf(acco[nt][r]);
      }
    }
  }
}

extern "C" void kernel_launch(void* const* d_in, const int* in_sizes, int n_in,
                              void* d_out, int out_size, void* d_ws, size_t ws_size,
                              hipStream_t stream) {
  const float* x     = (const float*)d_in[0];
  const float* wqkv  = (const float*)d_in[1];
  const float* wproj = (const float*)d_in[2];
  const float* qn_w  = (const float*)d_in[3];
  const float* qn_b  = (const float*)d_in[4];
  const float* kn_w  = (const float*)d_in[5];
  const float* kn_b  = (const float*)d_in[6];
  const float* bias  = (const float*)d_in[7];
  const float* bsc   = (const float*)d_in[8];
  float* out = (float*)d_out;

  unsigned short* xb  = (unsigned short*)d_ws;
  unsigned short* wqb = xb + NX;
  unsigned short* wpb = wqb + NQW;
  unsigned short* qws = wpb + NPW;
  unsigned short* kws = qws + 34078720UL;          // BH*65*64
  unsigned short* vws = kws + 34078720UL;
  unsigned short* aws = vws + 41943040UL;          // BH*64*80

  cast3_kernel<<<37376, 256, 0, stream>>>(x, wqkv, wproj, xb, wqb, wpb);
  gemm256_kernel<0, 12><<<1560, 512, 0, stream>>>(xb, wqb, qws, kws, vws, nullptr,
                                                  qn_w, qn_b, kn_w, kn_b);
  attn_kernel<<<8192, 256, 0, stream>>>(qws, kws, vws, bias, bsc, aws);
  gemm256_kernel<1, 4><<<520, 512, 0, stream>>>(aws, wpb, nullptr, nullptr, nullptr, out,
                                                nullptr, nullptr, nullptr, nullptr);
}

// Round 7
// 733.347 us; speedup vs baseline: 1.0174x; 1.0174x over previous
//
#include <hip/hip_runtime.h>
#include <stdint.h>

#define HEADS 16
#define BSZ 512
#define NTOK 65
#define MTOK (BSZ * NTOK)   // 33280 = 260*128 = 130*256
#define NX  34078720UL      // x elems
#define NQW 3145728UL       // w_qkv elems
#define NPW 1048576UL       // w_proj elems

typedef __attribute__((ext_vector_type(8))) short bf16x8;
typedef __attribute__((ext_vector_type(4))) float f32x4;

__device__ __forceinline__ unsigned short f2bf(float f) {
  unsigned u = __float_as_uint(f);
  u += 0x7FFFu + ((u >> 16) & 1u);          // RNE
  return (unsigned short)(u >> 16);
}

// ---------------- fp32 -> bf16 cast of x, w_qkv, w_proj ----------------
__global__ __launch_bounds__(256) void cast3_kernel(
    const float* __restrict__ x, const float* __restrict__ wq, const float* __restrict__ wp,
    unsigned short* __restrict__ xb, unsigned short* __restrict__ wqb, unsigned short* __restrict__ wpb) {
  size_t u = ((size_t)blockIdx.x * 256 + threadIdx.x) * 4;
  const float* src; unsigned short* dst; size_t off;
  if (u < NX)            { src = x;  dst = xb;  off = u; }
  else if (u < NX + NQW) { src = wq; dst = wqb; off = u - NX; }
  else                   { src = wp; dst = wpb; off = u - NX - NQW; }
  float4 v = *(const float4*)(src + off);
  ushort4 o;
  o.x = f2bf(v.x); o.y = f2bf(v.y); o.z = f2bf(v.z); o.w = f2bf(v.w);
  *(ushort4*)(dst + off) = o;
}

// ========= 256x256-tile bf16 GEMM (C = A[M,1024] @ B[N,1024]^T), 8 waves =========
// R1/R4-verified structure (~333 us on gemm0): BK=64, double-buffered 128 KB LDS,
// stage tile t+1 into the DEAD buffer at the top of tile t's compute, 4 phases of
// {ds_read subtile; s_barrier; setprio(1); 16 MFMA; setprio(0)}, boundary
// __syncthreads() drain. Chunk-XOR swizzle (0 bank conflicts measured).
// Race-free: writes only buf^1, reads only buf, one fence per K-tile.
// NOTE: counted-vmcnt variants tried twice (R2 regressed, R4-attempt corrupted) —
// keep this 1-deep form.
// MODE 0: fused LayerNorm epilogue + q/k/v scatter (NBN=12). MODE 1: fp32 out (NBN=4).
template <int MODE, int NBN>
__global__ __launch_bounds__(512, 2) void gemm256_kernel(
    const unsigned short* __restrict__ A, const unsigned short* __restrict__ Bm,
    unsigned short* __restrict__ qws, unsigned short* __restrict__ kws,
    unsigned short* __restrict__ vws, float* __restrict__ outp,
    const float* __restrict__ qn_w, const float* __restrict__ qn_b,
    const float* __restrict__ kn_w, const float* __restrict__ kn_b) {
  __shared__ unsigned short As0[256 * 64];
  __shared__ unsigned short Bs0[256 * 64];
  __shared__ unsigned short As1[256 * 64];
  __shared__ unsigned short Bs1[256 * 64];
  const int tid = threadIdx.x;
  const int wid = tid >> 6, lane = tid & 63;
  const int lrow = lane & 15, lk = lane >> 4;
  const int wm = wid >> 2, wn = wid & 3;

  // XCD-aware bijective swizzle (gridDim.x % 8 == 0 for both launches)
  const int chunk = (int)gridDim.x >> 3;
  const int orig = blockIdx.x;
  const int wg = (orig & 7) * chunk + (orig >> 3);
  const int bm = wg / NBN, bn = wg - bm * NBN;

  const size_t arow0 = (size_t)bm * 256, brow0 = (size_t)bn * 256;

  // per-thread staging sources: 4 chunks of A + 4 of B per K-tile
  const unsigned short* pA[4];
  const unsigned short* pB[4];
  int dstc[4];
#pragma unroll
  for (int j = 0; j < 4; ++j) {
    int ci = j * 512 + tid;
    int row = ci >> 3;
    int k8 = (ci & 7) ^ (row & 7);           // logical k-chunk stored at slot ci&7
    pA[j] = A + (arow0 + row) * 1024 + k8 * 8;
    pB[j] = Bm + (brow0 + row) * 1024 + k8 * 8;
    dstc[j] = (j * 512 + wid * 64) * 4;      // uint units (wave-uniform base)
  }

  f32x4 acc[2][4][4] = {};

  auto stage = [&](unsigned short* __restrict__ dA, unsigned short* __restrict__ dB, int ktn) {
    const int koff = ktn * 64;
#pragma unroll
    for (int j = 0; j < 4; ++j) {
      __builtin_amdgcn_global_load_lds(
          (const __attribute__((address_space(1))) unsigned int*)(pA[j] + koff),
          (__attribute__((address_space(3))) unsigned int*)dA + dstc[j], 16, 0, 0);
      __builtin_amdgcn_global_load_lds(
          (const __attribute__((address_space(1))) unsigned int*)(pB[j] + koff),
          (__attribute__((address_space(3))) unsigned int*)dB + dstc[j], 16, 0, 0);
    }
  };

  auto ktile = [&](const unsigned short* __restrict__ RA, const unsigned short* __restrict__ RB,
                   unsigned short* __restrict__ WA, unsigned short* __restrict__ WB, int ktn) {
    if (ktn < 16) stage(WA, WB, ktn);        // prefetch next K-tile into dead buffer
#pragma unroll
    for (int kk = 0; kk < 2; ++kk) {
      const int cpos8 = ((kk * 4 + lk) ^ (lrow & 7)) * 8;
      bf16x8 bv[4];
#pragma unroll
      for (int nt = 0; nt < 4; ++nt)
        bv[nt] = *(const bf16x8*)&RB[(wn * 64 + nt * 16 + lrow) * 64 + cpos8];
#pragma unroll
      for (int mh = 0; mh < 2; ++mh) {       // phase: 4 ds_read A + 16 MFMA
        bf16x8 av[4];
#pragma unroll
        for (int mt = 0; mt < 4; ++mt)
          av[mt] = *(const bf16x8*)&RA[(wm * 128 + mh * 64 + mt * 16 + lrow) * 64 + cpos8];
        __builtin_amdgcn_s_barrier();
        __builtin_amdgcn_s_setprio(1);
#pragma unroll
        for (int mt = 0; mt < 4; ++mt)
#pragma unroll
          for (int nt = 0; nt < 4; ++nt)
            acc[mh][mt][nt] =
                __builtin_amdgcn_mfma_f32_16x16x32_bf16(av[mt], bv[nt], acc[mh][mt][nt], 0, 0, 0);
        __builtin_amdgcn_s_setprio(0);
      }
    }
    __syncthreads();                          // vmcnt(0)+lgkmcnt(0)+barrier: kt+1 ready
  };

  stage(As0, Bs0, 0);                         // prologue
  __syncthreads();

#pragma unroll 1
  for (int kt2 = 0; kt2 < 8; ++kt2) {
    ktile(As0, Bs0, As1, Bs1, 2 * kt2 + 1);
    ktile(As1, Bs1, As0, Bs0, 2 * kt2 + 2);
  }

  if (MODE == 0) {
    // ---- fused LN epilogue + q/k/v scatter (256-wide tile indexing) ----
    const int sec = bn >> 2;                  // 0:q 1:k 2:v (block-uniform; 4 tiles/sec)
    const int h0 = ((bn & 3) << 2) + wn;      // head (wave-uniform; wave = one head)
    const float qsc = (sec == 0) ? 0.125f : 1.0f;
    float wv[4], bvv[4];
    if (sec < 2) {
      const float* wp_ = sec ? kn_w : qn_w;
      const float* bp_ = sec ? kn_b : qn_b;
#pragma unroll
      for (int nt = 0; nt < 4; ++nt) {
        wv[nt] = wp_[nt * 16 + lrow];
        bvv[nt] = bp_[nt * 16 + lrow];
      }
    }
    unsigned short* qk_dst = sec ? kws : qws;
#pragma unroll
    for (int mh = 0; mh < 2; ++mh)
#pragma unroll
      for (int mt = 0; mt < 4; ++mt)
#pragma unroll
        for (int r = 0; r < 4; ++r) {
          int grow = bm * 256 + wm * 128 + mh * 64 + mt * 16 + lk * 4 + r;
          int b = grow / 65, nn = grow - b * 65;   // const div -> magic mul
          int bh = b * HEADS + h0;
          if (sec < 2) {
            float s = 0.f, s2 = 0.f;
#pragma unroll
            for (int nt = 0; nt < 4; ++nt) {
              float f = acc[mh][mt][nt][r];
              s += f; s2 += f * f;
            }
            s += __shfl_xor(s, 1); s2 += __shfl_xor(s2, 1);
            s += __shfl_xor(s, 2); s2 += __shfl_xor(s2, 2);
            s += __shfl_xor(s, 4); s2 += __shfl_xor(s2, 4);
            s += __shfl_xor(s, 8); s2 += __shfl_xor(s2, 8);
            float mu = s * 0.015625f;
            float rstd = rsqrtf(s2 * 0.015625f - mu * mu + 1e-5f);
            size_t base = ((size_t)bh * 65 + nn) * 64;
#pragma unroll
            for (int nt = 0; nt < 4; ++nt)
              qk_dst[base + nt * 16 + lrow] =
                  f2bf(((acc[mh][mt][nt][r] - mu) * rstd * wv[nt] + bvv[nt]) * qsc);
          } else {
#pragma unroll
            for (int nt = 0; nt < 4; ++nt)
              vws[((size_t)bh * 64 + nt * 16 + lrow) * 80 + nn] = f2bf(acc[mh][mt][nt][r]);
          }
        }
  } else {
    // ---- fp32 store epilogue ----
    const size_t cb = (size_t)bn * 256 + wn * 64 + lrow;
#pragma unroll
    for (int mh = 0; mh < 2; ++mh)
#pragma unroll
      for (int mt = 0; mt < 4; ++mt)
#pragma unroll
        for (int r = 0; r < 4; ++r) {
          float* rp = outp +
              (size_t)(bm * 256 + wm * 128 + mh * 64 + mt * 16 + lk * 4 + r) * 1024 + cb;
#pragma unroll
          for (int nt = 0; nt < 4; ++nt) rp[nt * 16] = acc[mh][mt][nt][r];
        }
  }
}

// ---------------- attention per (b,h): S=qk^T, softmax, O=PV ----------------
// q,k already LayerNormed (+q scale) by gemm0. Staging via global_load_lds.
// 320 threads = 5 waves: ONE 16-row strip per wave in both MFMA phases (was
// 5 strips on 4 waves -> wave 0 was a 2x straggler on the critical path).
// LDS 36 KB (qk region reused for P after QK^T) -> 4 blocks/CU.
__global__ __launch_bounds__(320, 4) void attn_kernel(
    const unsigned short* __restrict__ qws, const unsigned short* __restrict__ kws,
    const unsigned short* __restrict__ vws,
    const float* __restrict__ bias, const float* __restrict__ bias_scale,
    unsigned short* __restrict__ aws) {
  __shared__ unsigned short qk_s[2 * 80 * 64];  // phase A: q rows 0..79 | k rows 0..79
                                                // phase B: P (80 x 128, swizzled chunks)
  __shared__ unsigned short v_s[64 * 128];      // vT rows d, 16 chunks (swizzled)
  const int tid = threadIdx.x;
  const int wid = tid >> 6;                     // 0..4
  const int bh = blockIdx.x;
  const int b = bh >> 4, h = bh & 15;
  const size_t qbase = (size_t)bh * 65 * 64;
  const size_t vbase = (size_t)bh * 64 * 80;

  // async stage q,k rows 0..63: 512 chunks each, rounds of 320 (all 5 waves)
  // then 192 (waves 0..2). Wave-uniform LDS bases; per-lane global sources.
  {
    int ci = tid;                               // 0..319
    int row = ci >> 3, k8 = (ci & 7) ^ (row & 7);
    __builtin_amdgcn_global_load_lds(
        (const __attribute__((address_space(1))) unsigned int*)(qws + qbase + row * 64 + k8 * 8),
        (__attribute__((address_space(3))) unsigned int*)qk_s + (size_t)(wid * 64) * 4,
        16, 0, 0);
    __builtin_amdgcn_global_load_lds(
        (const __attribute__((address_space(1))) unsigned int*)(kws + qbase + row * 64 + k8 * 8),
        (__attribute__((address_space(3))) unsigned int*)qk_s + (size_t)(640 + wid * 64) * 4,
        16, 0, 0);
  }
  if (wid < 3) {
    int ci = 320 + tid;                         // 320..511
    int row = ci >> 3, k8 = (ci & 7) ^ (row & 7);
    __builtin_amdgcn_global_load_lds(
        (const __attribute__((address_space(1))) unsigned int*)(qws + qbase + row * 64 + k8 * 8),
        (__attribute__((address_space(3))) unsigned int*)qk_s + (size_t)(320 + wid * 64) * 4,
        16, 0, 0);
    __builtin_amdgcn_global_load_lds(
        (const __attribute__((address_space(1))) unsigned int*)(kws + qbase + row * 64 + k8 * 8),
        (__attribute__((address_space(3))) unsigned int*)qk_s + (size_t)(640 + 320 + wid * 64) * 4,
        16, 0, 0);
  }
  // row 64 (8 chunks each) via plain copy; row&7==0 so no swizzle change.
  // q/k rows 65..79 stay uninitialized: S cols>=65 are masked to -1e30 before use,
  // and S rows>=65 only ever feed O rows>=65 which are never stored.
  if (tid < 8) {
    bf16x8 tq = *(const bf16x8*)&qws[qbase + 64 * 64 + tid * 8];
    *(bf16x8*)&qk_s[64 * 64 + tid * 8] = tq;
  } else if (tid < 16) {
    int t = tid - 8;
    bf16x8 tk = *(const bf16x8*)&kws[qbase + 64 * 64 + t * 8];
    *(bf16x8*)&qk_s[5120 + 64 * 64 + t * 8] = tk;
  }
  // async stage vT: 64 rows x 16 chunks = 1024 chunks: 3 rounds of 320 + 64 (wave 0)
  // (chunks >=10 read adjacent garbage; they only multiply exact-zero P columns)
#pragma unroll
  for (int it = 0; it < 3; ++it) {
    int ci = it * 320 + tid;
    int d = ci >> 4, cs = ci & 15;
    int c = cs ^ (d & 7);
    __builtin_amdgcn_global_load_lds(
        (const __attribute__((address_space(1))) unsigned int*)(vws + vbase + d * 80 + c * 8),
        (__attribute__((address_space(3))) unsigned int*)v_s + (size_t)(it * 320 + wid * 64) * 4,
        16, 0, 0);
  }
  if (wid == 0) {
    int ci = 960 + tid;                         // 960..1023
    int d = ci >> 4, cs = ci & 15;
    int c = cs ^ (d & 7);
    __builtin_amdgcn_global_load_lds(
        (const __attribute__((address_space(1))) unsigned int*)(vws + vbase + d * 80 + c * 8),
        (__attribute__((address_space(3))) unsigned int*)v_s + (size_t)(960) * 4,
        16, 0, 0);
  }
  __syncthreads();

  const int lane = tid & 63;
  const int lrow = lane & 15, lk = lane >> 4;
  const float bsc = *bias_scale;
  const unsigned short* q_s = qk_s;
  const unsigned short* k_s = qk_s + 5120;
  unsigned short* p_s = qk_s;                     // P overlays q|k after the barrier
  const int s = wid;                              // this wave's 16-row strip (0..4)

  // S = q@k^T (+bias, mask) then softmax, packed bf16 held in registers.
  unsigned int pk[5][2];
  {
    f32x4 accs[5] = {};
#pragma unroll
    for (int kk = 0; kk < 2; ++kk) {
      const int cpos = (kk * 4 + lk) ^ (lrow & 7);
      bf16x8 af = *(const bf16x8*)&q_s[(s * 16 + lrow) * 64 + cpos * 8];
#pragma unroll
      for (int nt = 0; nt < 5; ++nt) {
        bf16x8 bv = *(const bf16x8*)&k_s[(nt * 16 + lrow) * 64 + cpos * 8];
        accs[nt] = __builtin_amdgcn_mfma_f32_16x16x32_bf16(af, bv, accs[nt], 0, 0, 0);
      }
    }
#pragma unroll
    for (int r = 0; r < 4; ++r) {
      int row = s * 16 + lk * 4 + r;
      int brow = row > 64 ? 64 : row;
      float vals[5];
#pragma unroll
      for (int nt = 0; nt < 5; ++nt) {
        int col = nt * 16 + lrow;
        float v = accs[nt][r];
        if (col < 65) v += bias[((size_t)h * 65 + brow) * 65 + col] * bsc;
        else v = -1e30f;
        vals[nt] = v;
      }
      float m = vals[0];
#pragma unroll
      for (int nt = 1; nt < 5; ++nt) m = fmaxf(m, vals[nt]);
      m = fmaxf(m, __shfl_xor(m, 1)); m = fmaxf(m, __shfl_xor(m, 2));
      m = fmaxf(m, __shfl_xor(m, 4)); m = fmaxf(m, __shfl_xor(m, 8));
      float ssum = 0.f;
#pragma unroll
      for (int nt = 0; nt < 5; ++nt) { vals[nt] = __expf(vals[nt] - m); ssum += vals[nt]; }
      ssum += __shfl_xor(ssum, 1); ssum += __shfl_xor(ssum, 2);
      ssum += __shfl_xor(ssum, 4); ssum += __shfl_xor(ssum, 8);
      float inv = 1.0f / ssum;
#pragma unroll
      for (int nt = 0; nt < 5; ++nt) {
        unsigned int u = (unsigned int)f2bf(vals[nt] * inv);
        if ((r & 1) == 0) pk[nt][r >> 1] = u;
        else pk[nt][r >> 1] |= u << 16;
      }
    }
  }

  __syncthreads();                 // all q/k reads complete before P overlays them

  // write P strip (cols 80..95 exact zero: PV k-step 2 covers cols 64..95;
  // chunks for cols 96..127 are never read by PV -> not written)
#pragma unroll
  for (int r = 0; r < 4; ++r) {
    int row = s * 16 + lk * 4 + r;
#pragma unroll
    for (int nt = 0; nt < 5; ++nt) {
      int col = nt * 16 + lrow;
      p_s[row * 128 + ((col >> 3) ^ (row & 7)) * 8 + (col & 7)] =
          (unsigned short)(pk[nt][r >> 1] >> ((r & 1) * 16));
    }
    {
      int col = 80 + lrow;
      p_s[row * 128 + ((col >> 3) ^ (row & 7)) * 8 + (col & 7)] = 0;
    }
  }
  __syncthreads();

  // O = P @ V  (k-dim 96 with zero pad), write [B*N, 1024] bf16
  const size_t obase = (size_t)b * 65 * 1024 + h * 64;
  {
    f32x4 acco[4] = {};
#pragma unroll
    for (int kk = 0; kk < 3; ++kk) {
      const int cpos = (kk * 4 + lk) ^ (lrow & 7);
      bf16x8 af = *(const bf16x8*)&p_s[(s * 16 + lrow) * 128 + cpos * 8];
#pragma unroll
      for (int nt = 0; nt < 4; ++nt) {
        bf16x8 bv = *(const bf16x8*)&v_s[(nt * 16 + lrow) * 128 + cpos * 8];
        acco[nt] = __builtin_amdgcn_mfma_f32_16x16x32_bf16(af, bv, acco[nt], 0, 0, 0);
      }
    }
#pragma unroll
    for (int r = 0; r < 4; ++r) {
      int row = s * 16 + lk * 4 + r;
      if (row < 65) {
#pragma unroll
        for (int nt = 0; nt < 4; ++nt)
          aws[obase + (size_t)row * 1024 + nt * 16 + lrow] = f2bf(acco[nt][r]);
      }
    }
  }
}

extern "C" void kernel_launch(void* const* d_in, const int* in_sizes, int n_in,
                              void* d_out, int out_size, void* d_ws, size_t ws_size,
                              hipStream_t stream) {
  const float* x     = (const float*)d_in[0];
  const float* wqkv  = (const float*)d_in[1];
  const float* wproj = (const float*)d_in[2];
  const float* qn_w  = (const float*)d_in[3];
  const float* qn_b  = (const float*)d_in[4];
  const float* kn_w  = (const float*)d_in[5];
  const float* kn_b  = (const float*)d_in[6];
  const float* bias  = (const float*)d_in[7];
  const float* bsc   = (const float*)d_in[8];
  float* out = (float*)d_out;

  unsigned short* xb  = (unsigned short*)d_ws;
  unsigned short* wqb = xb + NX;
  unsigned short* wpb = wqb + NQW;
  unsigned short* qws = wpb + NPW;
  unsigned short* kws = qws + 34078720UL;          // BH*65*64
  unsigned short* vws = kws + 34078720UL;
  unsigned short* aws = vws + 41943040UL;          // BH*64*80

  cast3_kernel<<<37376, 256, 0, stream>>>(x, wqkv, wproj, xb, wqb, wpb);
  gemm256_kernel<0, 12><<<1560, 512, 0, stream>>>(xb, wqb, qws, kws, vws, nullptr,
                                                  qn_w, qn_b, kn_w, kn_b);
  attn_kernel<<<8192, 320, 0, stream>>>(qws, kws, vws, bias, bsc, aws);
  gemm256_kernel<1, 4><<<520, 512, 0, stream>>>(aws, wpb, nullptr, nullptr, nullptr, out,
                                                nullptr, nullptr, nullptr, nullptr);
}

// Round 8
// 729.374 us; speedup vs baseline: 1.0229x; 1.0054x over previous
//
#include <hip/hip_runtime.h>
#include <stdint.h>

#define HEADS 16
#define BSZ 512
#define NTOK 65
#define MTOK (BSZ * NTOK)   // 33280 = 260*128 = 130*256
#define NX  34078720UL      // x elems
#define NQW 3145728UL       // w_qkv elems
#define NPW 1048576UL       // w_proj elems

typedef __attribute__((ext_vector_type(8))) short bf16x8;
typedef __attribute__((ext_vector_type(4))) float f32x4;

#define CFENCE asm volatile("" ::: "memory")

__device__ __forceinline__ unsigned short f2bf(float f) {
  unsigned u = __float_as_uint(f);
  u += 0x7FFFu + ((u >> 16) & 1u);          // RNE
  return (unsigned short)(u >> 16);
}

// ---------------- fp32 -> bf16 cast of x, w_qkv, w_proj ----------------
__global__ __launch_bounds__(256) void cast3_kernel(
    const float* __restrict__ x, const float* __restrict__ wq, const float* __restrict__ wp,
    unsigned short* __restrict__ xb, unsigned short* __restrict__ wqb, unsigned short* __restrict__ wpb) {
  size_t u = ((size_t)blockIdx.x * 256 + threadIdx.x) * 4;
  const float* src; unsigned short* dst; size_t off;
  if (u < NX)            { src = x;  dst = xb;  off = u; }
  else if (u < NX + NQW) { src = wq; dst = wqb; off = u - NX; }
  else                   { src = wp; dst = wpb; off = u - NX - NQW; }
  float4 v = *(const float4*)(src + off);
  ushort4 o;
  o.x = f2bf(v.x); o.y = f2bf(v.y); o.z = f2bf(v.z); o.w = f2bf(v.w);
  *(ushort4*)(dst + off) = o;
}

// ===== 256x256-tile bf16 GEMM, 8 waves, 4-phase counted-vmcnt pipeline =====
// C = A[M,1024] @ B[N,1024]^T. BK=64; LDS 128 KB laid out as
// [buf2][mat2][kk2][row256][slot4][8elem]  (kk-slab = one (mat, 32-k half) = 16 KB).
// Slot swizzle: phys slot = k4 ^ ((row>>1)&3) (involution; SQ_LDS_BANK_CONFLICT=0
// measured on this exact pattern in R2). Staging: wave-uniform LDS dst (R4 form),
// per-lane swizzled global source.  **R5's bug was here: global source was missing
// the `tau*64` K-tile offset — every tile re-staged k[0,64). Fixed.**
// Schedule per K-tile t (4 phases; buf = t&1; t+2 shares buf with t):
//   ph0(kk0,mh0): rd B0,A0(mh0) | stage A-kk1[t+1]   (other buf; last read t-1 ph3)
//   ph1(kk0,mh1): rd A0(mh1)    | stage B-kk0[t+2]   (B-kk0[t] last ds_read ph0)
//   ph2(kk1,mh0): rd B1,A1(mh0) | stage A-kk0[t+2]   (A-kk0[t] last read ph1)
//   ph3(kk1,mh1): rd A1(mh1)    | stage B-kk1[t+2]   (B-kk1[t] last ds_read ph2)
//                 then s_waitcnt vmcnt(6): 3 newest half-tiles (all for t+2) stay
//                 in flight; everything for t+1 landed. NEVER vmcnt(0) mid-loop.
// Each phase: {reads; stage; bar; setprio(1); 16 MFMA; setprio(0); bar} with
// compiler fences pinning stage issues into their phase. Stage at ph(i) only
// overwrites regions last-read at ph(i-1), separated by ph(i-1)'s end barrier.
// Prologue: t0's 4 halves + t1's {B0,A0,B1} (14 loads), vmcnt(6), barrier.
// Tail: t=14 stages only A-kk1[15], ends vmcnt(0); t=15 computes only.
// MODE 0: fused LayerNorm epilogue + q/k/v scatter (NBN=12). MODE 1: fp32 out (NBN=4).
template <int MODE, int NBN>
__global__ __launch_bounds__(512, 2) void gemm256_kernel(
    const unsigned short* __restrict__ A, const unsigned short* __restrict__ Bm,
    unsigned short* __restrict__ qws, unsigned short* __restrict__ kws,
    unsigned short* __restrict__ vws, float* __restrict__ outp,
    const float* __restrict__ qn_w, const float* __restrict__ qn_b,
    const float* __restrict__ kn_w, const float* __restrict__ kn_b) {
  __shared__ unsigned short L[65536];   // 128 KB
  const int tid = threadIdx.x;
  const int wid = tid >> 6, lane = tid & 63;
  const int lrow = lane & 15, lk = lane >> 4;
  const int wm = wid >> 2, wn = wid & 3;

  // XCD-aware bijective swizzle (gridDim.x % 8 == 0 for both launches)
  const int chunk = (int)gridDim.x >> 3;
  const int orig = blockIdx.x;
  const int wg = (orig & 7) * chunk + (orig >> 3);
  const int bm = wg / NBN, bn = wg - bm * NBN;

  const unsigned short* Abase = A + (size_t)bm * 256 * 1024;
  const unsigned short* Bbase = Bm + (size_t)bn * 256 * 1024;

  // staging geometry: one slab = 1024 chunks (256 rows x 4 slots); thread stages
  // ci = tid and tid+512. LDS dst wave-uniform (R4-proven form) + HW lane*16.
  int srow[2], sk4x8[2], dstu[2];
#pragma unroll
  for (int j = 0; j < 2; ++j) {
    int ci = j * 512 + tid;
    int row = ci >> 2, slot = ci & 3;
    srow[j] = row;
    sk4x8[j] = (slot ^ ((row >> 1) & 3)) * 8;   // logical k4-chunk stored at this slot
    dstu[j] = (j * 512 + wid * 64) * 4;         // uint units, wave-uniform
  }
  const int cpos8 = (lk ^ ((lrow >> 1) & 3)) * 8;  // frag-read slot (elems)

  f32x4 acc[2][4][4] = {};

  auto stageA = [&](int kk, int tau) {
    const int baseu = (tau & 1) * 16384 + kk * 4096;
#pragma unroll
    for (int j = 0; j < 2; ++j)
      __builtin_amdgcn_global_load_lds(
          (const __attribute__((address_space(1))) unsigned int*)
              (Abase + (size_t)srow[j] * 1024 + tau * 64 + kk * 32 + sk4x8[j]),
          (__attribute__((address_space(3))) unsigned int*)L + baseu + dstu[j], 16, 0, 0);
  };
  auto stageB = [&](int kk, int tau) {
    const int baseu = (tau & 1) * 16384 + 8192 + kk * 4096;
#pragma unroll
    for (int j = 0; j < 2; ++j)
      __builtin_amdgcn_global_load_lds(
          (const __attribute__((address_space(1))) unsigned int*)
              (Bbase + (size_t)srow[j] * 1024 + tau * 64 + kk * 32 + sk4x8[j]),
          (__attribute__((address_space(3))) unsigned int*)L + baseu + dstu[j], 16, 0, 0);
  };

  auto rdB = [&](int t, int kk, bf16x8 (&bv)[4]) {
    const int base = (t & 1) * 32768 + 16384 + kk * 8192 + cpos8;
#pragma unroll
    for (int nt = 0; nt < 4; ++nt)
      bv[nt] = *(const bf16x8*)&L[base + (wn * 64 + nt * 16 + lrow) * 32];
  };
  auto rdA = [&](int t, int kk, int mh, bf16x8 (&av)[4]) {
    const int base = (t & 1) * 32768 + kk * 8192 + cpos8;
    const int r0 = wm * 128 + mh * 64;
#pragma unroll
    for (int mt = 0; mt < 4; ++mt)
      av[mt] = *(const bf16x8*)&L[base + (r0 + mt * 16 + lrow) * 32];
  };
  auto mfma16 = [&](bf16x8 (&av)[4], bf16x8 (&bv)[4], f32x4 (&ac)[4][4]) {
    __builtin_amdgcn_s_setprio(1);
#pragma unroll
    for (int mt = 0; mt < 4; ++mt)
#pragma unroll
      for (int nt = 0; nt < 4; ++nt)
        ac[mt][nt] = __builtin_amdgcn_mfma_f32_16x16x32_bf16(av[mt], bv[nt], ac[mt][nt], 0, 0, 0);
    __builtin_amdgcn_s_setprio(0);
  };

  auto ktile = [&](int t, int st, int wc) {
    bf16x8 bv[4], av[4];
    // ph0 (kk0, mh0)
    rdB(t, 0, bv); rdA(t, 0, 0, av);
    if (st & 1) stageA(1, t + 1);
    CFENCE; __builtin_amdgcn_s_barrier(); CFENCE;
    mfma16(av, bv, acc[0]);
    CFENCE; __builtin_amdgcn_s_barrier(); CFENCE;
    // ph1 (kk0, mh1)
    rdA(t, 0, 1, av);
    if (st & 2) stageB(0, t + 2);
    CFENCE; __builtin_amdgcn_s_barrier(); CFENCE;
    mfma16(av, bv, acc[1]);
    CFENCE; __builtin_amdgcn_s_barrier(); CFENCE;
    // ph2 (kk1, mh0)
    rdB(t, 1, bv); rdA(t, 1, 0, av);
    if (st & 4) stageA(0, t + 2);
    CFENCE; __builtin_amdgcn_s_barrier(); CFENCE;
    mfma16(av, bv, acc[0]);
    CFENCE; __builtin_amdgcn_s_barrier(); CFENCE;
    // ph3 (kk1, mh1)
    rdA(t, 1, 1, av);
    if (st & 8) stageB(1, t + 2);
    CFENCE; __builtin_amdgcn_s_barrier(); CFENCE;
    mfma16(av, bv, acc[1]);
    if (wc == 6)      asm volatile("s_waitcnt vmcnt(6)" ::: "memory");
    else if (wc == 0) asm volatile("s_waitcnt vmcnt(0)" ::: "memory");
    CFENCE; __builtin_amdgcn_s_barrier(); CFENCE;
  };

  // prologue: K-tile 0 fully + K-tile 1's {B-kk0, A-kk0, B-kk1} (14 loads)
  stageB(0, 0); stageA(0, 0); stageB(1, 0); stageA(1, 0);
  stageB(0, 1); stageA(0, 1); stageB(1, 1);
  asm volatile("s_waitcnt vmcnt(6)" ::: "memory");   // K-tile 0 landed; t1's 3 in flight
  __builtin_amdgcn_s_barrier(); CFENCE;

#pragma unroll 1
  for (int t = 0; t < 14; ++t) ktile(t, 0xF, 6);
  ktile(14, 0x1, 0);                                  // last stage: A-kk1[15]; drain
  ktile(15, 0x0, -1);

  if (MODE == 0) {
    // ---- fused LN epilogue + q/k/v scatter (256-wide tile indexing) ----
    const int sec = bn >> 2;                  // 0:q 1:k 2:v (block-uniform; 4 tiles/sec)
    const int h0 = ((bn & 3) << 2) + wn;      // head (wave-uniform; wave = one head)
    const float qsc = (sec == 0) ? 0.125f : 1.0f;
    float wv[4], bvv[4];
    if (sec < 2) {
      const float* wp_ = sec ? kn_w : qn_w;
      const float* bp_ = sec ? kn_b : qn_b;
#pragma unroll
      for (int nt = 0; nt < 4; ++nt) {
        wv[nt] = wp_[nt * 16 + lrow];
        bvv[nt] = bp_[nt * 16 + lrow];
      }
    }
    unsigned short* qk_dst = sec ? kws : qws;
#pragma unroll
    for (int mh = 0; mh < 2; ++mh)
#pragma unroll
      for (int mt = 0; mt < 4; ++mt)
#pragma unroll
        for (int r = 0; r < 4; ++r) {
          int grow = bm * 256 + wm * 128 + mh * 64 + mt * 16 + lk * 4 + r;
          int b = grow / 65, nn = grow - b * 65;   // const div -> magic mul
          int bh = b * HEADS + h0;
          if (sec < 2) {
            float s = 0.f, s2 = 0.f;
#pragma unroll
            for (int nt = 0; nt < 4; ++nt) {
              float f = acc[mh][mt][nt][r];
              s += f; s2 += f * f;
            }
            s += __shfl_xor(s, 1); s2 += __shfl_xor(s2, 1);
            s += __shfl_xor(s, 2); s2 += __shfl_xor(s2, 2);
            s += __shfl_xor(s, 4); s2 += __shfl_xor(s2, 4);
            s += __shfl_xor(s, 8); s2 += __shfl_xor(s2, 8);
            float mu = s * 0.015625f;
            float rstd = rsqrtf(s2 * 0.015625f - mu * mu + 1e-5f);
            size_t base = ((size_t)bh * 65 + nn) * 64;
#pragma unroll
            for (int nt = 0; nt < 4; ++nt)
              qk_dst[base + nt * 16 + lrow] =
                  f2bf(((acc[mh][mt][nt][r] - mu) * rstd * wv[nt] + bvv[nt]) * qsc);
          } else {
#pragma unroll
            for (int nt = 0; nt < 4; ++nt)
              vws[((size_t)bh * 64 + nt * 16 + lrow) * 80 + nn] = f2bf(acc[mh][mt][nt][r]);
          }
        }
  } else {
    // ---- fp32 store epilogue ----
    const size_t cb = (size_t)bn * 256 + wn * 64 + lrow;
#pragma unroll
    for (int mh = 0; mh < 2; ++mh)
#pragma unroll
      for (int mt = 0; mt < 4; ++mt)
#pragma unroll
        for (int r = 0; r < 4; ++r) {
          float* rp = outp +
              (size_t)(bm * 256 + wm * 128 + mh * 64 + mt * 16 + lk * 4 + r) * 1024 + cb;
#pragma unroll
          for (int nt = 0; nt < 4; ++nt) rp[nt * 16] = acc[mh][mt][nt][r];
        }
  }
}

// ---------------- attention per (b,h): S=qk^T, softmax, O=PV ----------------
// q,k already LayerNormed (+q scale) by gemm0. Staging via global_load_lds.
// 320 threads = 5 waves: one 16-row strip per wave in both MFMA phases.
// LDS 36 KB (qk region reused for P after QK^T) -> 4 blocks/CU.
__global__ __launch_bounds__(320, 4) void attn_kernel(
    const unsigned short* __restrict__ qws, const unsigned short* __restrict__ kws,
    const unsigned short* __restrict__ vws,
    const float* __restrict__ bias, const float* __restrict__ bias_scale,
    unsigned short* __restrict__ aws) {
  __shared__ unsigned short qk_s[2 * 80 * 64];  // phase A: q rows 0..79 | k rows 0..79
                                                // phase B: P (80 x 128, swizzled chunks)
  __shared__ unsigned short v_s[64 * 128];      // vT rows d, 16 chunks (swizzled)
  const int tid = threadIdx.x;
  const int wid = tid >> 6;                     // 0..4
  const int bh = blockIdx.x;
  const int b = bh >> 4, h = bh & 15;
  const size_t qbase = (size_t)bh * 65 * 64;
  const size_t vbase = (size_t)bh * 64 * 80;

  // async stage q,k rows 0..63: 512 chunks each, rounds of 320 then 192 (waves 0..2)
  {
    int ci = tid;                               // 0..319
    int row = ci >> 3, k8 = (ci & 7) ^ (row & 7);
    __builtin_amdgcn_global_load_lds(
        (const __attribute__((address_space(1))) unsigned int*)(qws + qbase + row * 64 + k8 * 8),
        (__attribute__((address_space(3))) unsigned int*)qk_s + (size_t)(wid * 64) * 4,
        16, 0, 0);
    __builtin_amdgcn_global_load_lds(
        (const __attribute__((address_space(1))) unsigned int*)(kws + qbase + row * 64 + k8 * 8),
        (__attribute__((address_space(3))) unsigned int*)qk_s + (size_t)(640 + wid * 64) * 4,
        16, 0, 0);
  }
  if (wid < 3) {
    int ci = 320 + tid;                         // 320..511
    int row = ci >> 3, k8 = (ci & 7) ^ (row & 7);
    __builtin_amdgcn_global_load_lds(
        (const __attribute__((address_space(1))) unsigned int*)(qws + qbase + row * 64 + k8 * 8),
        (__attribute__((address_space(3))) unsigned int*)qk_s + (size_t)(320 + wid * 64) * 4,
        16, 0, 0);
    __builtin_amdgcn_global_load_lds(
        (const __attribute__((address_space(1))) unsigned int*)(kws + qbase + row * 64 + k8 * 8),
        (__attribute__((address_space(3))) unsigned int*)qk_s + (size_t)(640 + 320 + wid * 64) * 4,
        16, 0, 0);
  }
  // row 64 (8 chunks each) via plain copy; row&7==0 so no swizzle change.
  if (tid < 8) {
    bf16x8 tq = *(const bf16x8*)&qws[qbase + 64 * 64 + tid * 8];
    *(bf16x8*)&qk_s[64 * 64 + tid * 8] = tq;
  } else if (tid < 16) {
    int t = tid - 8;
    bf16x8 tk = *(const bf16x8*)&kws[qbase + 64 * 64 + t * 8];
    *(bf16x8*)&qk_s[5120 + 64 * 64 + t * 8] = tk;
  }
  // async stage vT: 1024 chunks: 3 rounds of 320 + 64 (wave 0)
#pragma unroll
  for (int it = 0; it < 3; ++it) {
    int ci = it * 320 + tid;
    int d = ci >> 4, cs = ci & 15;
    int c = cs ^ (d & 7);
    __builtin_amdgcn_global_load_lds(
        (const __attribute__((address_space(1))) unsigned int*)(vws + vbase + d * 80 + c * 8),
        (__attribute__((address_space(3))) unsigned int*)v_s + (size_t)(it * 320 + wid * 64) * 4,
        16, 0, 0);
  }
  if (wid == 0) {
    int ci = 960 + tid;                         // 960..1023
    int d = ci >> 4, cs = ci & 15;
    int c = cs ^ (d & 7);
    __builtin_amdgcn_global_load_lds(
        (const __attribute__((address_space(1))) unsigned int*)(vws + vbase + d * 80 + c * 8),
        (__attribute__((address_space(3))) unsigned int*)v_s + (size_t)(960) * 4,
        16, 0, 0);
  }
  __syncthreads();

  const int lane = tid & 63;
  const int lrow = lane & 15, lk = lane >> 4;
  const float bsc = *bias_scale;
  const unsigned short* q_s = qk_s;
  const unsigned short* k_s = qk_s + 5120;
  unsigned short* p_s = qk_s;                     // P overlays q|k after the barrier
  const int s = wid;                              // this wave's 16-row strip (0..4)

  // S = q@k^T (+bias, mask) then softmax, packed bf16 held in registers.
  unsigned int pk[5][2];
  {
    f32x4 accs[5] = {};
#pragma unroll
    for (int kk = 0; kk < 2; ++kk) {
      const int cpos = (kk * 4 + lk) ^ (lrow & 7);
      bf16x8 af = *(const bf16x8*)&q_s[(s * 16 + lrow) * 64 + cpos * 8];
#pragma unroll
      for (int nt = 0; nt < 5; ++nt) {
        bf16x8 bv = *(const bf16x8*)&k_s[(nt * 16 + lrow) * 64 + cpos * 8];
        accs[nt] = __builtin_amdgcn_mfma_f32_16x16x32_bf16(af, bv, accs[nt], 0, 0, 0);
      }
    }
#pragma unroll
    for (int r = 0; r < 4; ++r) {
      int row = s * 16 + lk * 4 + r;
      int brow = row > 64 ? 64 : row;
      float vals[5];
#pragma unroll
      for (int nt = 0; nt < 5; ++nt) {
        int col = nt * 16 + lrow;
        float v = accs[nt][r];
        if (col < 65) v += bias[((size_t)h * 65 + brow) * 65 + col] * bsc;
        else v = -1e30f;
        vals[nt] = v;
      }
      float m = vals[0];
#pragma unroll
      for (int nt = 1; nt < 5; ++nt) m = fmaxf(m, vals[nt]);
      m = fmaxf(m, __shfl_xor(m, 1)); m = fmaxf(m, __shfl_xor(m, 2));
      m = fmaxf(m, __shfl_xor(m, 4)); m = fmaxf(m, __shfl_xor(m, 8));
      float ssum = 0.f;
#pragma unroll
      for (int nt = 0; nt < 5; ++nt) { vals[nt] = __expf(vals[nt] - m); ssum += vals[nt]; }
      ssum += __shfl_xor(ssum, 1); ssum += __shfl_xor(ssum, 2);
      ssum += __shfl_xor(ssum, 4); ssum += __shfl_xor(ssum, 8);
      float inv = 1.0f / ssum;
#pragma unroll
      for (int nt = 0; nt < 5; ++nt) {
        unsigned int u = (unsigned int)f2bf(vals[nt] * inv);
        if ((r & 1) == 0) pk[nt][r >> 1] = u;
        else pk[nt][r >> 1] |= u << 16;
      }
    }
  }

  __syncthreads();                 // all q/k reads complete before P overlays them

#pragma unroll
  for (int r = 0; r < 4; ++r) {
    int row = s * 16 + lk * 4 + r;
#pragma unroll
    for (int nt = 0; nt < 5; ++nt) {
      int col = nt * 16 + lrow;
      p_s[row * 128 + ((col >> 3) ^ (row & 7)) * 8 + (col & 7)] =
          (unsigned short)(pk[nt][r >> 1] >> ((r & 1) * 16));
    }
    {
      int col = 80 + lrow;
      p_s[row * 128 + ((col >> 3) ^ (row & 7)) * 8 + (col & 7)] = 0;
    }
  }
  __syncthreads();

  // O = P @ V  (k-dim 96 with zero pad), write [B*N, 1024] bf16
  const size_t obase = (size_t)b * 65 * 1024 + h * 64;
  {
    f32x4 acco[4] = {};
#pragma unroll
    for (int kk = 0; kk < 3; ++kk) {
      const int cpos = (kk * 4 + lk) ^ (lrow & 7);
      bf16x8 af = *(const bf16x8*)&p_s[(s * 16 + lrow) * 128 + cpos * 8];
#pragma unroll
      for (int nt = 0; nt < 4; ++nt) {
        bf16x8 bv = *(const bf16x8*)&v_s[(nt * 16 + lrow) * 128 + cpos * 8];
        acco[nt] = __builtin_amdgcn_mfma_f32_16x16x32_bf16(af, bv, acco[nt], 0, 0, 0);
      }
    }
#pragma unroll
    for (int r = 0; r < 4; ++r) {
      int row = s * 16 + lk * 4 + r;
      if (row < 65) {
#pragma unroll
        for (int nt = 0; nt < 4; ++nt)
          aws[obase + (size_t)row * 1024 + nt * 16 + lrow] = f2bf(acco[nt][r]);
      }
    }
  }
}

extern "C" void kernel_launch(void* const* d_in, const int* in_sizes, int n_in,
                              void* d_out, int out_size, void* d_ws, size_t ws_size,
                              hipStream_t stream) {
  const float* x     = (const float*)d_in[0];
  const float* wqkv  = (const float*)d_in[1];
  const float* wproj = (const float*)d_in[2];
  const float* qn_w  = (const float*)d_in[3];
  const float* qn_b  = (const float*)d_in[4];
  const float* kn_w  = (const float*)d_in[5];
  const float* kn_b  = (const float*)d_in[6];
  const float* bias  = (const float*)d_in[7];
  const float* bsc   = (const float*)d_in[8];
  float* out = (float*)d_out;

  unsigned short* xb  = (unsigned short*)d_ws;
  unsigned short* wqb = xb + NX;
  unsigned short* wpb = wqb + NQW;
  unsigned short* qws = wpb + NPW;
  unsigned short* kws = qws + 34078720UL;          // BH*65*64
  unsigned short* vws = kws + 34078720UL;
  unsigned short* aws = vws + 41943040UL;          // BH*64*80

  cast3_kernel<<<37376, 256, 0, stream>>>(x, wqkv, wproj, xb, wqb, wpb);
  gemm256_kernel<0, 12><<<1560, 512, 0, stream>>>(xb, wqb, qws, kws, vws, nullptr,
                                                  qn_w, qn_b, kn_w, kn_b);
  attn_kernel<<<8192, 320, 0, stream>>>(qws, kws, vws, bias, bsc, aws);
  gemm256_kernel<1, 4><<<520, 512, 0, stream>>>(aws, wpb, nullptr, nullptr, nullptr, out,
                                                nullptr, nullptr, nullptr, nullptr);
}